// Round 19
// baseline (82.604 us; speedup 1.0000x reference)
//
#include <hip/hip_runtime.h>
#include <hip/hip_bf16.h>

#define N_ATOMS 4096
#define NSLAB 32
#define PSTRIDE 8192   // per-type packed stride (duplicated window)
#define KSTEPS_TOTAL 27
typedef unsigned long long ull;
typedef __attribute__((ext_vector_type(8))) __bf16 bf16x8;
typedef __attribute__((ext_vector_type(4))) float f32x4;
typedef __attribute__((ext_vector_type(8))) unsigned short u16x8;

__device__ __forceinline__ float wrapr(float d, float box, float rbox) {
    return d - box * rintf(d * rbox);
}

__device__ __forceinline__ float ftanh(float x) {
    float t = __expf(2.0f * x);
    return 1.0f - 2.0f * __builtin_amdgcn_rcpf(t + 1.0f);
}

// Single prep dispatch. Blocks 0..15: self-contained slab scatter; packed
// duplicated for wrap-free select windows. Blocks 16..: weight packing.
__global__ __launch_bounds__(256) void fill_kernel(
    const float* __restrict__ xyz, const int* __restrict__ types,
    int* __restrict__ slabOffG, int* __restrict__ cntG,
    int* __restrict__ lists, int* __restrict__ posArr,
    float4* __restrict__ packed, float* __restrict__ out,
    const float* __restrict__ w1, const float* __restrict__ w2,
    const float* __restrict__ w3, __hip_bfloat16* __restrict__ Wp)
{
    const int bid = blockIdx.x;
    const int tid = threadIdx.x;

    if (bid < 16) {
        __shared__ int lhAll[64];
        __shared__ int lhPre[64];
        __shared__ int base[64];
        __shared__ int cur[64];
        __shared__ int cntS[2];

        if (tid < 64) { lhAll[tid] = 0; lhPre[tid] = 0; cur[tid] = 0; }
        __syncthreads();

        const int myBase = bid * 256;
        for (int m = tid; m < N_ATOMS; m += 256) {
            int t = types[m];
            int slab = min(NSLAB - 1, (int)(xyz[3*m+2] * (NSLAB / 40.0f)));
            int ts = t * NSLAB + slab;
            atomicAdd(&lhAll[ts], 1);
            if (m < myBase) atomicAdd(&lhPre[ts], 1);
        }
        __syncthreads();

        if (tid < 64) {
            int tot = lhAll[tid];
            int v = tot;
            #pragma unroll
            for (int off = 1; off < 32; off <<= 1) {
                int u = __shfl_up(v, off);
                if ((tid & 31) >= off) v += u;
            }
            base[tid] = v - tot;
            int t = tid >> 5, s = tid & 31;
            if (s == 31) cntS[t] = v;
            if (bid == 0) {
                slabOffG[t * (NSLAB + 1) + s + 1] = v;
                if (s == 0)  slabOffG[t * (NSLAB + 1)] = 0;
                if (s == 31) cntG[t] = v;
            }
        }
        if (bid == 0 && tid == 0) out[0] = 0.0f;
        __syncthreads();

        int i = myBase + tid;
        int t = types[i];
        float z = xyz[3*i+2];
        int slab = min(NSLAB - 1, (int)(z * (NSLAB / 40.0f)));
        int ts = t * NSLAB + slab;
        int idx = base[ts] + lhPre[ts] + atomicAdd(&cur[ts], 1);
        lists[t * N_ATOMS + idx] = i;
        posArr[i] = idx;
        float4 pv = make_float4(xyz[3*i+0], xyz[3*i+1], z,
                                __uint_as_float((unsigned)i));
        packed[t * PSTRIDE + idx] = pv;
        packed[t * PSTRIDE + idx + cntS[t]] = pv;
    } else {
        int idx = (bid - 16) * 256 + tid;
        int n = idx & 255;
        int k = (idx >> 8) % 864;
        int t = idx / (864 * 256);
        int ksg, kr; float v;
        if (k < 352)      { kr = k;       ksg = kr >> 5;        v = w1[((size_t)t*352 + kr)*256 + n]; }
        else if (k < 608) { kr = k - 352; ksg = 11 + (kr >> 5); v = w2[((size_t)t*256 + kr)*256 + n]; }
        else              { kr = k - 608; ksg = 19 + (kr >> 5); v = w3[((size_t)t*256 + kr)*256 + n]; }
        int l  = (((kr & 31) >> 3) << 4) | (n & 15);
        int e  = kr & 7;
        int nt = n >> 4;
        size_t dst = ((((size_t)t*KSTEPS_TOTAL + ksg)*16 + nt) << 9) + (l << 3) + e;
        Wp[dst] = __float2bfloat16(v);
    }
}

// WAVE-PER-TASK select: 256-thread block = 4 waves, each wave = one
// (atom,type) task. No __syncthreads anywhere (single-wave LDS is ordered).
// z-slab window (wrap-free), 64-bucket histogram + wave shuffle scan +
// cursor scatter, exact within-bucket rank by 43-bit key -> sorted top-128.
__global__ __launch_bounds__(256) void select_kernel(
    const float* __restrict__ xyz, const float* __restrict__ box,
    const int* __restrict__ cnt, const float4* __restrict__ packed,
    const int* __restrict__ slabOffG,
    const int* __restrict__ types, const int* __restrict__ posArr,
    __hip_bfloat16* __restrict__ descB, float* __restrict__ aX,
    float* __restrict__ aD, float* __restrict__ lfD, int* __restrict__ lfJ)
{
    __shared__ ull skAll[4][512];
    __shared__ int histAll[4][64];
    __shared__ int baseAll[4][64];

    const int tid = threadIdx.x;
    const int wv  = tid >> 6;
    const int ln  = tid & 63;
    const int task = blockIdx.x * 4 + wv;
    const int i   = task >> 1;
    const int t   = task & 1;
    const int n   = cnt[t];

    ull* sk    = skAll[wv];
    int* hist  = histAll[wv];
    int* basev = baseAll[wv];

    const float bx = box[0], by = box[1], bz = box[2];
    const float rbx = 1.0f/bx, rby = 1.0f/by, rbz = 1.0f/bz;
    const float xi = xyz[3*i+0], yi = xyz[3*i+1], zi = xyz[3*i+2];
    const unsigned ibits = (unsigned)i;
    const float4* pk = packed + t * PSTRIDE;
    const int* soff = slabOffG + t * (NSLAB + 1);

    float T = __powf(38.2f * bx * by * bz / (float)n, 0.6666667f);   // ~160 nbrs
    float Twin = -1.0f, scale = 1.0f;
    int A = 0, L = n;
    int count = 0;
    float d2r[24];   // caches first 1536 window slots; tail recomputed (rare)

#define DIST(mm, dst) { \
    float4 p = pk[A + (mm)]; \
    dst = __builtin_inff(); \
    if (__float_as_uint(p.w) != ibits) { \
        float ax_ = fabsf(xi - p.x); \
        float ay_ = fabsf(yi - p.y); \
        float az_ = fabsf(zi - p.z); \
        float mx = fminf(ax_, bx - ax_); \
        float my = fminf(ay_, by - ay_); \
        float mz = fminf(az_, bz - az_); \
        dst = mx*mx + my*my + mz*mz; } }

    for (int attempt = 0; attempt < 8; ++attempt) {
        if (T > Twin) {
            float r = sqrtf(T);
            int slo = (int)floorf((zi - r) * (NSLAB / 40.0f)) - 1;
            int shi = (int)floorf((zi + r) * (NSLAB / 40.0f)) + 1;
            int nsl = shi - slo + 1;
            if (nsl >= NSLAB) { A = 0; L = n; }
            else {
                int ss = slo & (NSLAB - 1);
                A = soff[ss];
                int send = ss + nsl;
                L = (send <= NSLAB) ? (soff[send] - A)
                                    : (n - A) + soff[send - NSLAB];
            }
            Twin = T;
            #pragma unroll
            for (int s = 0; s < 24; ++s) {
                d2r[s] = __builtin_inff();
                if ((s << 6) < L) {
                    int m = ln + (s << 6);
                    if (m < L) DIST(m, d2r[s])
                }
            }
        }
        scale = 64.0f / T;

        hist[ln] = 0;
        #pragma unroll
        for (int s = 0; s < 24; ++s) {
            if (d2r[s] < T)
                atomicAdd(&hist[min(63, (int)(d2r[s] * scale))], 1);
        }
        for (int m = 1536 + ln; m < L; m += 64) {   // exactness tail (rare)
            float d2; DIST(m, d2)
            if (d2 < T) atomicAdd(&hist[min(63, (int)(d2 * scale))], 1);
        }
        int h = hist[ln];
        int v = h;
        #pragma unroll
        for (int off = 1; off < 64; off <<= 1) {
            int u = __shfl_up(v, off);
            if (ln >= off) v += u;
        }
        count = __shfl(v, 63);
        basev[ln] = v - h;     // exclusive start; doubles as cursor
        if (count >= 128 && count <= 511) break;
        T *= (count < 128) ? 1.9f : 0.6f;
    }

    // scatter keys into bucket-ordered slots
    #pragma unroll
    for (int s = 0; s < 24; ++s) {
        if (d2r[s] < T) {
            int b = min(63, (int)(d2r[s] * scale));
            int pp = atomicAdd(&basev[b], 1);
            if (pp < 512) {
                int m = ln + (s << 6);
                unsigned j = __float_as_uint(pk[A + m].w);
                sk[pp] = ((ull)__float_as_uint(d2r[s]) << 12) | j;
            }
        }
    }
    for (int m = 1536 + ln; m < L; m += 64) {       // exactness tail (rare)
        float d2; DIST(m, d2)
        if (d2 < T) {
            int b = min(63, (int)(d2 * scale));
            int pp = atomicAdd(&basev[b], 1);
            if (pp < 512) {
                unsigned j = __float_as_uint(pk[A + m].w);
                sk[pp] = ((ull)__float_as_uint(d2) << 12) | j;
            }
        }
    }
    const int cnt2 = min(count, 512);

    // exact rank (within-bucket compare), outputs
    const int ti = types[i];
    const int pi = posArr[i];
    __hip_bfloat16* drow = descB + ((size_t)ti * N_ATOMS + pi) * 256;
    for (int s2 = ln; s2 < cnt2; s2 += 64) {
        ull k = sk[s2];
        float d2 = __uint_as_float((unsigned)(k >> 12));
        int b = min(63, (int)(d2 * scale));
        int hh = hist[b];
        int r = s2;
        if (hh > 1) {
            int bs = basev[b] - hh;    // cursor end minus bucket size
            int hi2 = min(bs + hh, cnt2);
            r = bs;
            for (int x = bs; x < hi2; ++x) r += (sk[x] < k) ? 1 : 0;
        }
        if (r < 128) {
            int j = (int)(k & 0xFFF);
            float dist = sqrtf(d2);
            drow[t * 128 + r] = __float2bfloat16(1.0f / (dist + 1e-16f));
            if (r < 16) {
                float dx = wrapr(xi - xyz[3*j+0], bx, rbx);
                float dy = wrapr(yi - xyz[3*j+1], by, rby);
                float dz = wrapr(zi - xyz[3*j+2], bz, rbz);
                int s3 = i * 32 + t * 16 + r;
                aX[3*s3+0] = dx; aX[3*s3+1] = dy; aX[3*s3+2] = dz;
                aD[s3] = dist;
            }
            if (r < 2) {
                lfD[i * 4 + t * 2 + r] = dist;
                lfJ[i * 4 + t * 2 + r] = j;
            }
        }
    }
#undef DIST
}

// Fused: local frame + rot features + 3-layer bf16-MFMA MLP + energy.
// Block = 8 atoms x 256 neurons, 4 waves. C/D: col=lane&15, row=(lane>>4)*4+reg.
__global__ __launch_bounds__(256) void mlp_fused_kernel(
    const int* __restrict__ cnt, const int* __restrict__ lists,
    const float* __restrict__ xyz, const float* __restrict__ box,
    const float* __restrict__ aX, const float* __restrict__ aD,
    const float* __restrict__ lfD, const int* __restrict__ lfJ,
    const __hip_bfloat16* __restrict__ descB,
    const __hip_bfloat16* __restrict__ Wp,
    const float* __restrict__ b1, const float* __restrict__ b2,
    const float* __restrict__ b3,
    const float* __restrict__ w4, const float* __restrict__ b4,
    float* __restrict__ out)
{
    __shared__ __hip_bfloat16 Dld[16 * 360];
    __shared__ __hip_bfloat16 Hld[16 * 264];
    __shared__ float b1s[256], b2s[256], b3s[256], w4s[256];
    __shared__ float red[4][16];
    __shared__ float Am[8][12];
    __shared__ int atoms[8];

    const int t   = blockIdx.y;
    const int n_t = cnt[t];
    const int p0  = blockIdx.x * 8;
    if (p0 >= n_t) return;
    const int nv  = min(8, n_t - p0);
    const int tid = threadIdx.x;
    const int w   = tid >> 6;
    const int l   = tid & 63;
    const int lane15 = l & 15;
    const float bx = box[0], by = box[1], bz = box[2];
    const float rbx = 1.0f/bx, rby = 1.0f/by, rbz = 1.0f/bz;

    b1s[tid] = b1[t * 256 + tid];
    b2s[tid] = b2[t * 256 + tid];
    b3s[tid] = b3[t * 256 + tid];
    w4s[tid] = w4[t * 256 + tid];
    if (tid < 8)
        atoms[tid] = (tid < nv) ? lists[t * N_ATOMS + p0 + tid] : -1;

    for (int c = tid; c < 16 * 44; c += 256) {
        int row = c / 44, kc = c - row * 44;
        u16x8 v = {0,0,0,0,0,0,0,0};
        if (row < nv && kc < 32)
            v = *(const u16x8*)&descB[((size_t)t*N_ATOMS + p0 + row)*256 + kc*8];
        *(u16x8*)&Dld[row * 360 + kc * 8] = v;
    }
    __syncthreads();

    if (tid < 8 && atoms[tid] >= 0) {
        const int a = atoms[tid];
        const float xi = xyz[3*a+0], yi = xyz[3*a+1], zi = xyz[3*a+2];
        float cd[4]; int cj[4];
        #pragma unroll
        for (int c = 0; c < 4; ++c) { cd[c] = lfD[a*4+c]; cj[c] = lfJ[a*4+c]; }
        int i0 = 0; float bm = cd[0];
        for (int c = 1; c < 4; ++c) if (cd[c] < bm) { bm = cd[c]; i0 = c; }
        int i1 = -1; float b1v = 3.4e38f;
        for (int c = 0; c < 4; ++c) { if (c == i0) continue; if (cd[c] < b1v) { b1v = cd[c]; i1 = c; } }

        int ja = cj[i0], jb = cj[i1];
        float da = cd[i0], db = cd[i1];
        float r0x = wrapr(xi - xyz[3*ja+0], bx, rbx) / (da + 1e-16f);
        float r0y = wrapr(yi - xyz[3*ja+1], by, rby) / (da + 1e-16f);
        float r0z = wrapr(zi - xyz[3*ja+2], bz, rbz) / (da + 1e-16f);
        float r1x = wrapr(xi - xyz[3*jb+0], bx, rbx) / (db + 1e-16f);
        float r1y = wrapr(yi - xyz[3*jb+1], by, rby) / (db + 1e-16f);
        float r1z = wrapr(zi - xyz[3*jb+2], bz, rbz) / (db + 1e-16f);
        float dot = r0x*r1x + r0y*r1y + r0z*r1z;
        float v2x = r1x - dot*r0x, v2y = r1y - dot*r0y, v2z = r1z - dot*r0z;
        float n2 = sqrtf(v2x*v2x + v2y*v2y + v2z*v2z);
        v2x /= n2; v2y /= n2; v2z /= n2;
        float v3x = r0y*r1z - r0z*r1y;
        float v3y = r0z*r1x - r0x*r1z;
        float v3z = r0x*r1y - r0y*r1x;
        float n3 = sqrtf(v3x*v3x + v3y*v3y + v3z*v3z);
        v3x /= n3; v3y /= n3; v3z /= n3;
        Am[tid][0]=r0x; Am[tid][1]=r0y; Am[tid][2]=r0z;
        Am[tid][3]=v2x; Am[tid][4]=v2y; Am[tid][5]=v2z;
        Am[tid][6]=v3x; Am[tid][7]=v3y; Am[tid][8]=v3z;
    }
    __syncthreads();

    if (tid < 128) {
        const int q = tid >> 4, s = tid & 15;
        const int a = atoms[q];
        if (a >= 0) {
            #pragma unroll
            for (int half = 0; half < 2; ++half) {
                int ss = s + (half << 4);
                int sidx = a * 32 + ss;
                float d  = aD[sidx];
                float dn = d + 1e-16f;
                float ax = aX[3*sidx+0] / dn;
                float ay = aX[3*sidx+1] / dn;
                float az = aX[3*sidx+2] / dn;
                float o0 = (Am[q][0]*ax + Am[q][1]*ay + Am[q][2]*az) / dn;
                float o1 = (Am[q][3]*ax + Am[q][4]*ay + Am[q][5]*az) / dn;
                float o2 = (Am[q][6]*ax + Am[q][7]*ay + Am[q][8]*az) / dn;
                Dld[q*360 + 256 + 3*ss + 0] = __float2bfloat16(o0);
                Dld[q*360 + 256 + 3*ss + 1] = __float2bfloat16(o1);
                Dld[q*360 + 256 + 3*ss + 2] = __float2bfloat16(o2);
            }
        }
    }
    __syncthreads();

    const __hip_bfloat16* wpt = Wp + (((size_t)t * KSTEPS_TOTAL * 16 + (w << 2)) << 9);
    const int aoff = ((l >> 4) << 3);
    const int rb   = ((l >> 4) << 2);

    f32x4 acc0 = {0,0,0,0}, acc1 = {0,0,0,0}, acc2 = {0,0,0,0}, acc3 = {0,0,0,0};

#define KSTEP(SRC, STRIDE, KSG) { \
    bf16x8 a = *(const bf16x8*)&SRC[lane15 * STRIDE + (ks << 5) + aoff]; \
    const __hip_bfloat16* wk = wpt + (((size_t)(KSG) << 13)) + (l << 3); \
    bf16x8 bv0 = *(const bf16x8*)(wk); \
    bf16x8 bv1 = *(const bf16x8*)(wk + 512); \
    bf16x8 bv2 = *(const bf16x8*)(wk + 1024); \
    bf16x8 bv3 = *(const bf16x8*)(wk + 1536); \
    acc0 = __builtin_amdgcn_mfma_f32_16x16x32_bf16(a, bv0, acc0, 0, 0, 0); \
    acc1 = __builtin_amdgcn_mfma_f32_16x16x32_bf16(a, bv1, acc1, 0, 0, 0); \
    acc2 = __builtin_amdgcn_mfma_f32_16x16x32_bf16(a, bv2, acc2, 0, 0, 0); \
    acc3 = __builtin_amdgcn_mfma_f32_16x16x32_bf16(a, bv3, acc3, 0, 0, 0); }

#define STORE_H(ACC, NT, DST, STRIDE, BS) if (rb < nv) { \
    int n = (w << 6) + ((NT) << 4) + lane15; \
    float bb = BS[n]; \
    DST[(rb + 0) * STRIDE + n] = __float2bfloat16(ftanh(ACC[0] + bb)); \
    DST[(rb + 1) * STRIDE + n] = __float2bfloat16(ftanh(ACC[1] + bb)); \
    DST[(rb + 2) * STRIDE + n] = __float2bfloat16(ftanh(ACC[2] + bb)); \
    DST[(rb + 3) * STRIDE + n] = __float2bfloat16(ftanh(ACC[3] + bb)); }

    #pragma unroll 2
    for (int ks = 0; ks < 11; ++ks) KSTEP(Dld, 360, ks)
    STORE_H(acc0, 0, Hld, 264, b1s)
    STORE_H(acc1, 1, Hld, 264, b1s)
    STORE_H(acc2, 2, Hld, 264, b1s)
    STORE_H(acc3, 3, Hld, 264, b1s)
    __syncthreads();

    acc0 = (f32x4){0,0,0,0}; acc1 = acc0; acc2 = acc0; acc3 = acc0;
    #pragma unroll 2
    for (int ks = 0; ks < 8; ++ks) KSTEP(Hld, 264, 11 + ks)
    __syncthreads();
    STORE_H(acc0, 0, Dld, 360, b2s)
    STORE_H(acc1, 1, Dld, 360, b2s)
    STORE_H(acc2, 2, Dld, 360, b2s)
    STORE_H(acc3, 3, Dld, 360, b2s)
    __syncthreads();

    acc0 = (f32x4){0,0,0,0}; acc1 = acc0; acc2 = acc0; acc3 = acc0;
    #pragma unroll 2
    for (int ks = 0; ks < 8; ++ks) KSTEP(Dld, 360, 19 + ks)

    float s0 = 0.f, s1 = 0.f, s2 = 0.f, s3 = 0.f;
#define EPART(ACC, NT) if (rb < nv) { \
    int n = (w << 6) + ((NT) << 4) + lane15; \
    float wv = w4s[n]; float bb = b3s[n]; \
    s0 += ftanh(ACC[0] + bb) * wv; s1 += ftanh(ACC[1] + bb) * wv; \
    s2 += ftanh(ACC[2] + bb) * wv; s3 += ftanh(ACC[3] + bb) * wv; }
    EPART(acc0, 0) EPART(acc1, 1) EPART(acc2, 2) EPART(acc3, 3)

    #pragma unroll
    for (int off = 1; off <= 8; off <<= 1) {
        s0 += __shfl_xor(s0, off);
        s1 += __shfl_xor(s1, off);
        s2 += __shfl_xor(s2, off);
        s3 += __shfl_xor(s3, off);
    }
    if (lane15 == 0) {
        red[w][rb + 0] = s0;
        red[w][rb + 1] = s1;
        red[w][rb + 2] = s2;
        red[w][rb + 3] = s3;
    }
    __syncthreads();

    if (tid < 16) {
        float e = red[0][tid] + red[1][tid] + red[2][tid] + red[3][tid];
        e = (tid < nv) ? (e + b4[t]) : 0.0f;
        #pragma unroll
        for (int off = 1; off <= 8; off <<= 1) e += __shfl_xor(e, off);
        if (tid == 0) atomicAdd(out, e);
    }
#undef KSTEP
#undef STORE_H
#undef EPART
}

extern "C" void kernel_launch(void* const* d_in, const int* in_sizes, int n_in,
                              void* d_out, int out_size, void* d_ws, size_t ws_size,
                              hipStream_t stream) {
    const float* xyz   = (const float*)d_in[0];
    const float* box   = (const float*)d_in[1];
    const int*   types = (const int*)  d_in[2];
    const float* w1 = (const float*)d_in[3];
    const float* b1 = (const float*)d_in[4];
    const float* w2 = (const float*)d_in[5];
    const float* b2 = (const float*)d_in[6];
    const float* w3 = (const float*)d_in[7];
    const float* b3 = (const float*)d_in[8];
    const float* w4 = (const float*)d_in[9];
    const float* b4 = (const float*)d_in[10];
    float* out = (float*)d_out;

    // workspace (4B units; 16B alignment preserved at packed/descB)
    float* p = (float*)d_ws;
    int*    cnt      = (int*)p;        p += 16;
    int*    slabOffG = (int*)p;        p += 68;
    int*    posArr   = (int*)p;        p += N_ATOMS;
    int*    lists    = (int*)p;        p += 2 * N_ATOMS;
    p += 12;                                            // pad to 16B
    float4* packed   = (float4*)p;     p += 2 * PSTRIDE * 4;
    float*  lfD      = p;              p += 4 * N_ATOMS;
    int*    lfJ      = (int*)p;        p += 4 * N_ATOMS;
    float*  aX       = p;              p += 96 * N_ATOMS;
    float*  aD       = p;              p += 32 * N_ATOMS;
    __hip_bfloat16* descB = (__hip_bfloat16*)p;         // 2*4096*256 bf16
    p += (size_t)2 * N_ATOMS * 256 / 2;
    __hip_bfloat16* Wp = (__hip_bfloat16*)p;            // 2*27*16*512 bf16
    p += (size_t)2 * KSTEPS_TOTAL * 16 * 512 / 2;

    fill_kernel<<<16 + (2 * 864 * 256) / 256, 256, 0, stream>>>(
        xyz, types, slabOffG, cnt, lists, posArr, packed, out, w1, w2, w3, Wp);
    select_kernel<<<2 * N_ATOMS / 4, 256, 0, stream>>>(
        xyz, box, cnt, packed, slabOffG, types, posArr, descB, aX, aD, lfD, lfJ);
    dim3 g(N_ATOMS / 8, 2);
    mlp_fused_kernel<<<g, 256, 0, stream>>>(cnt, lists, xyz, box, aX, aD, lfD, lfJ,
                                            descB, Wp, b1, b2, b3, w4, b4, out);
}

// Round 20
// 67.642 us; speedup vs baseline: 1.2212x; 1.2212x over previous
//
#include <hip/hip_runtime.h>
#include <hip/hip_bf16.h>

#define N_ATOMS 4096
#define NSLAB 32
#define PSTRIDE 8192   // per-type packed stride (duplicated window)
#define KSTEPS_TOTAL 27
typedef unsigned long long ull;
typedef __attribute__((ext_vector_type(8))) __bf16 bf16x8;
typedef __attribute__((ext_vector_type(4))) float f32x4;
typedef __attribute__((ext_vector_type(8))) unsigned short u16x8;

__device__ __forceinline__ float wrapr(float d, float box, float rbox) {
    return d - box * rintf(d * rbox);
}

__device__ __forceinline__ float ftanh(float x) {
    float t = __expf(2.0f * x);
    return 1.0f - 2.0f * __builtin_amdgcn_rcpf(t + 1.0f);
}

// Single prep dispatch. Blocks 0..15: self-contained slab scatter (each block
// recomputes the full histogram + its prefix); packed duplicated for
// wrap-free select windows. Blocks 16..: bf16 MFMA weight packing.
__global__ __launch_bounds__(256) void fill_kernel(
    const float* __restrict__ xyz, const int* __restrict__ types,
    int* __restrict__ slabOffG, int* __restrict__ cntG,
    int* __restrict__ lists, int* __restrict__ posArr,
    float4* __restrict__ packed, float* __restrict__ out,
    const float* __restrict__ w1, const float* __restrict__ w2,
    const float* __restrict__ w3, __hip_bfloat16* __restrict__ Wp)
{
    const int bid = blockIdx.x;
    const int tid = threadIdx.x;

    if (bid < 16) {
        __shared__ int lhAll[64];
        __shared__ int lhPre[64];
        __shared__ int base[64];
        __shared__ int cur[64];
        __shared__ int cntS[2];

        if (tid < 64) { lhAll[tid] = 0; lhPre[tid] = 0; cur[tid] = 0; }
        __syncthreads();

        const int myBase = bid * 256;
        for (int m = tid; m < N_ATOMS; m += 256) {
            int t = types[m];
            int slab = min(NSLAB - 1, (int)(xyz[3*m+2] * (NSLAB / 40.0f)));
            int ts = t * NSLAB + slab;
            atomicAdd(&lhAll[ts], 1);
            if (m < myBase) atomicAdd(&lhPre[ts], 1);
        }
        __syncthreads();

        if (tid < 64) {
            int tot = lhAll[tid];
            int v = tot;   // segmented 32-wide inclusive scan in one wave
            #pragma unroll
            for (int off = 1; off < 32; off <<= 1) {
                int u = __shfl_up(v, off);
                if ((tid & 31) >= off) v += u;
            }
            base[tid] = v - tot;
            int t = tid >> 5, s = tid & 31;
            if (s == 31) cntS[t] = v;
            if (bid == 0) {
                slabOffG[t * (NSLAB + 1) + s + 1] = v;
                if (s == 0)  slabOffG[t * (NSLAB + 1)] = 0;
                if (s == 31) cntG[t] = v;
            }
        }
        if (bid == 0 && tid == 0) out[0] = 0.0f;
        __syncthreads();

        int i = myBase + tid;
        int t = types[i];
        float z = xyz[3*i+2];
        int slab = min(NSLAB - 1, (int)(z * (NSLAB / 40.0f)));
        int ts = t * NSLAB + slab;
        int idx = base[ts] + lhPre[ts] + atomicAdd(&cur[ts], 1);
        lists[t * N_ATOMS + idx] = i;
        posArr[i] = idx;
        float4 pv = make_float4(xyz[3*i+0], xyz[3*i+1], z,
                                __uint_as_float((unsigned)i));
        packed[t * PSTRIDE + idx] = pv;
        packed[t * PSTRIDE + idx + cntS[t]] = pv;   // duplicate: wrap-free reads
    } else {
        int idx = (bid - 16) * 256 + tid;   // exactly 2*864*256 threads
        int n = idx & 255;
        int k = (idx >> 8) % 864;
        int t = idx / (864 * 256);
        int ksg, kr; float v;
        if (k < 352)      { kr = k;       ksg = kr >> 5;        v = w1[((size_t)t*352 + kr)*256 + n]; }
        else if (k < 608) { kr = k - 352; ksg = 11 + (kr >> 5); v = w2[((size_t)t*256 + kr)*256 + n]; }
        else              { kr = k - 608; ksg = 19 + (kr >> 5); v = w3[((size_t)t*256 + kr)*256 + n]; }
        int l  = (((kr & 31) >> 3) << 4) | (n & 15);
        int e  = kr & 7;
        int nt = n >> 4;
        size_t dst = ((((size_t)t*KSTEPS_TOTAL + ksg)*16 + nt) << 9) + (l << 3) + e;
        Wp[dst] = __float2bfloat16(v);
    }
}

// One block per (atom, type): z-slab window (wrap-free via duplicated packed),
// threshold target ~160 nbrs, bucket histogram + scan + cursor scatter, exact
// within-bucket rank by 43-bit key (d2bits<<12 | j) -> exact sorted top-128.
__global__ __launch_bounds__(256) void select_kernel(
    const float* __restrict__ xyz, const float* __restrict__ box,
    const int* __restrict__ cnt, const float4* __restrict__ packed,
    const int* __restrict__ slabOffG,
    const int* __restrict__ types, const int* __restrict__ posArr,
    __hip_bfloat16* __restrict__ descB, float* __restrict__ aX,
    float* __restrict__ aD, float* __restrict__ lfD, int* __restrict__ lfJ)
{
    __shared__ ull sortedk[512];
    __shared__ int hist[256];
    __shared__ int basev[256];
    __shared__ int wsum[4];

    const int i   = blockIdx.x >> 1;
    const int t   = blockIdx.x & 1;
    const int tid = threadIdx.x;
    const int n   = cnt[t];
    const float bx = box[0], by = box[1], bz = box[2];
    const float rbx = 1.0f/bx, rby = 1.0f/by, rbz = 1.0f/bz;
    const float xi = xyz[3*i+0], yi = xyz[3*i+1], zi = xyz[3*i+2];
    const unsigned ibits = (unsigned)i;
    const float4* pk = packed + t * PSTRIDE;
    const int* soff = slabOffG + t * (NSLAB + 1);

    float T = __powf(38.2f * bx * by * bz / (float)n, 0.6666667f);   // ~160 nbrs
    float Twin = -1.0f, scale = 1.0f;
    int A = 0, L = n;
    int count = 0;
    float d2r[10];

    for (int attempt = 0; attempt < 8; ++attempt) {
        if (T > Twin) {
            float r = sqrtf(T);
            int slo = (int)floorf((zi - r) * (NSLAB / 40.0f)) - 1;
            int shi = (int)floorf((zi + r) * (NSLAB / 40.0f)) + 1;
            int nsl = shi - slo + 1;
            if (nsl >= NSLAB) { A = 0; L = n; }
            else {
                int ss = slo & (NSLAB - 1);
                A = soff[ss];
                int send = ss + nsl;
                L = (send <= NSLAB) ? (soff[send] - A)
                                    : (n - A) + soff[send - NSLAB];
            }
            Twin = T;
            scale = 256.0f / Twin;
            #pragma unroll
            for (int c = 0; c < 10; ++c) {
                d2r[c] = __builtin_inff();
                if ((c << 8) < L) {
                    int m = tid + (c << 8);
                    if (m < L) {
                        float4 p = pk[A + m];           // wrap-free (duplicated)
                        if (__float_as_uint(p.w) != ibits) {
                            float ax_ = fabsf(xi - p.x);
                            float ay_ = fabsf(yi - p.y);
                            float az_ = fabsf(zi - p.z);
                            float mx = fminf(ax_, bx - ax_);
                            float my = fminf(ay_, by - ay_);
                            float mz = fminf(az_, bz - az_);
                            d2r[c] = mx*mx + my*my + mz*mz;
                        }
                    }
                }
            }
        }

        hist[tid] = 0;
        __syncthreads();
        #pragma unroll
        for (int c = 0; c < 10; ++c) {
            if (d2r[c] < T)
                atomicAdd(&hist[min(255, (int)(d2r[c] * scale))], 1);
        }
        __syncthreads();
        int h = hist[tid];
        int v = h;
        #pragma unroll
        for (int off = 1; off < 64; off <<= 1) {
            int u = __shfl_up(v, off);
            if ((tid & 63) >= off) v += u;
        }
        if ((tid & 63) == 63) wsum[tid >> 6] = v;
        __syncthreads();
        int woff = 0;
        #pragma unroll
        for (int w2 = 0; w2 < 3; ++w2) if (w2 < (tid >> 6)) woff += wsum[w2];
        basev[tid] = v + woff - h;     // exclusive start; doubles as cursor
        count = wsum[0] + wsum[1] + wsum[2] + wsum[3];
        __syncthreads();
        if (count >= 128 && count <= 511) break;
        T *= (count < 128) ? 1.9f : 0.6f;
    }

    #pragma unroll
    for (int c = 0; c < 10; ++c) {
        if (d2r[c] < T) {
            int b = min(255, (int)(d2r[c] * scale));
            int pp = atomicAdd(&basev[b], 1);
            if (pp < 512) {
                int m = tid + (c << 8);
                unsigned j = __float_as_uint(pk[A + m].w);
                sortedk[pp] = ((ull)__float_as_uint(d2r[c]) << 12) | j;
            }
        }
    }
    __syncthreads();
    const int cnt2 = min(count, 512);

    const int ti = types[i];
    const int pi = posArr[i];
    __hip_bfloat16* drow = descB + ((size_t)ti * N_ATOMS + pi) * 256;
    for (int s = tid; s < cnt2; s += 256) {
        ull k = sortedk[s];
        float d2 = __uint_as_float((unsigned)(k >> 12));
        int b = min(255, (int)(d2 * scale));
        int hh = hist[b];
        int r = s;
        if (hh > 1) {
            int bs = basev[b] - hh;    // cursor end minus bucket size = start
            int hi2 = min(bs + hh, cnt2);
            r = bs;
            for (int x = bs; x < hi2; ++x) r += (sortedk[x] < k) ? 1 : 0;
        }
        if (r < 128) {
            int j = (int)(k & 0xFFF);
            float dist = sqrtf(d2);
            drow[t * 128 + r] = __float2bfloat16(1.0f / (dist + 1e-16f));
            if (r < 16) {
                float dx = wrapr(xi - xyz[3*j+0], bx, rbx);
                float dy = wrapr(yi - xyz[3*j+1], by, rby);
                float dz = wrapr(zi - xyz[3*j+2], bz, rbz);
                int s2 = i * 32 + t * 16 + r;
                aX[3*s2+0] = dx; aX[3*s2+1] = dy; aX[3*s2+2] = dz;
                aD[s2] = dist;
            }
            if (r < 2) {
                lfD[i * 4 + t * 2 + r] = dist;
                lfJ[i * 4 + t * 2 + r] = j;
            }
        }
    }
}

// Fused: local frame + rot features + 3-layer bf16-MFMA MLP + energy.
// Block = 8 atoms x 256 neurons, 4 waves. C/D: col=lane&15, row=(lane>>4)*4+reg.
__global__ __launch_bounds__(256) void mlp_fused_kernel(
    const int* __restrict__ cnt, const int* __restrict__ lists,
    const float* __restrict__ xyz, const float* __restrict__ box,
    const float* __restrict__ aX, const float* __restrict__ aD,
    const float* __restrict__ lfD, const int* __restrict__ lfJ,
    const __hip_bfloat16* __restrict__ descB,
    const __hip_bfloat16* __restrict__ Wp,
    const float* __restrict__ b1, const float* __restrict__ b2,
    const float* __restrict__ b3,
    const float* __restrict__ w4, const float* __restrict__ b4,
    float* __restrict__ out)
{
    __shared__ __hip_bfloat16 Dld[16 * 360];
    __shared__ __hip_bfloat16 Hld[16 * 264];
    __shared__ float b1s[256], b2s[256], b3s[256], w4s[256];
    __shared__ float red[4][16];
    __shared__ float Am[8][12];
    __shared__ int atoms[8];

    const int t   = blockIdx.y;
    const int n_t = cnt[t];
    const int p0  = blockIdx.x * 8;
    if (p0 >= n_t) return;
    const int nv  = min(8, n_t - p0);
    const int tid = threadIdx.x;
    const int w   = tid >> 6;
    const int l   = tid & 63;
    const int lane15 = l & 15;
    const float bx = box[0], by = box[1], bz = box[2];
    const float rbx = 1.0f/bx, rby = 1.0f/by, rbz = 1.0f/bz;

    b1s[tid] = b1[t * 256 + tid];
    b2s[tid] = b2[t * 256 + tid];
    b3s[tid] = b3[t * 256 + tid];
    w4s[tid] = w4[t * 256 + tid];
    if (tid < 8)
        atoms[tid] = (tid < nv) ? lists[t * N_ATOMS + p0 + tid] : -1;

    for (int c = tid; c < 16 * 44; c += 256) {
        int row = c / 44, kc = c - row * 44;
        u16x8 v = {0,0,0,0,0,0,0,0};
        if (row < nv && kc < 32)
            v = *(const u16x8*)&descB[((size_t)t*N_ATOMS + p0 + row)*256 + kc*8];
        *(u16x8*)&Dld[row * 360 + kc * 8] = v;
    }
    __syncthreads();

    if (tid < 8 && atoms[tid] >= 0) {
        const int a = atoms[tid];
        const float xi = xyz[3*a+0], yi = xyz[3*a+1], zi = xyz[3*a+2];
        float cd[4]; int cj[4];
        #pragma unroll
        for (int c = 0; c < 4; ++c) { cd[c] = lfD[a*4+c]; cj[c] = lfJ[a*4+c]; }
        int i0 = 0; float bm = cd[0];
        for (int c = 1; c < 4; ++c) if (cd[c] < bm) { bm = cd[c]; i0 = c; }
        int i1 = -1; float b1v = 3.4e38f;
        for (int c = 0; c < 4; ++c) { if (c == i0) continue; if (cd[c] < b1v) { b1v = cd[c]; i1 = c; } }

        int ja = cj[i0], jb = cj[i1];
        float da = cd[i0], db = cd[i1];
        float r0x = wrapr(xi - xyz[3*ja+0], bx, rbx) / (da + 1e-16f);
        float r0y = wrapr(yi - xyz[3*ja+1], by, rby) / (da + 1e-16f);
        float r0z = wrapr(zi - xyz[3*ja+2], bz, rbz) / (da + 1e-16f);
        float r1x = wrapr(xi - xyz[3*jb+0], bx, rbx) / (db + 1e-16f);
        float r1y = wrapr(yi - xyz[3*jb+1], by, rby) / (db + 1e-16f);
        float r1z = wrapr(zi - xyz[3*jb+2], bz, rbz) / (db + 1e-16f);
        float dot = r0x*r1x + r0y*r1y + r0z*r1z;
        float v2x = r1x - dot*r0x, v2y = r1y - dot*r0y, v2z = r1z - dot*r0z;
        float n2 = sqrtf(v2x*v2x + v2y*v2y + v2z*v2z);
        v2x /= n2; v2y /= n2; v2z /= n2;
        float v3x = r0y*r1z - r0z*r1y;
        float v3y = r0z*r1x - r0x*r1z;
        float v3z = r0x*r1y - r0y*r1x;
        float n3 = sqrtf(v3x*v3x + v3y*v3y + v3z*v3z);
        v3x /= n3; v3y /= n3; v3z /= n3;
        Am[tid][0]=r0x; Am[tid][1]=r0y; Am[tid][2]=r0z;
        Am[tid][3]=v2x; Am[tid][4]=v2y; Am[tid][5]=v2z;
        Am[tid][6]=v3x; Am[tid][7]=v3y; Am[tid][8]=v3z;
    }
    __syncthreads();

    if (tid < 128) {
        const int q = tid >> 4, s = tid & 15;
        const int a = atoms[q];
        if (a >= 0) {
            #pragma unroll
            for (int half = 0; half < 2; ++half) {
                int ss = s + (half << 4);
                int sidx = a * 32 + ss;
                float d  = aD[sidx];
                float dn = d + 1e-16f;
                float ax = aX[3*sidx+0] / dn;
                float ay = aX[3*sidx+1] / dn;
                float az = aX[3*sidx+2] / dn;
                float o0 = (Am[q][0]*ax + Am[q][1]*ay + Am[q][2]*az) / dn;
                float o1 = (Am[q][3]*ax + Am[q][4]*ay + Am[q][5]*az) / dn;
                float o2 = (Am[q][6]*ax + Am[q][7]*ay + Am[q][8]*az) / dn;
                Dld[q*360 + 256 + 3*ss + 0] = __float2bfloat16(o0);
                Dld[q*360 + 256 + 3*ss + 1] = __float2bfloat16(o1);
                Dld[q*360 + 256 + 3*ss + 2] = __float2bfloat16(o2);
            }
        }
    }
    __syncthreads();

    const __hip_bfloat16* wpt = Wp + (((size_t)t * KSTEPS_TOTAL * 16 + (w << 2)) << 9);
    const int aoff = ((l >> 4) << 3);
    const int rb   = ((l >> 4) << 2);

    f32x4 acc0 = {0,0,0,0}, acc1 = {0,0,0,0}, acc2 = {0,0,0,0}, acc3 = {0,0,0,0};

#define KSTEP(SRC, STRIDE, KSG) { \
    bf16x8 a = *(const bf16x8*)&SRC[lane15 * STRIDE + (ks << 5) + aoff]; \
    const __hip_bfloat16* wk = wpt + (((size_t)(KSG) << 13)) + (l << 3); \
    bf16x8 bv0 = *(const bf16x8*)(wk); \
    bf16x8 bv1 = *(const bf16x8*)(wk + 512); \
    bf16x8 bv2 = *(const bf16x8*)(wk + 1024); \
    bf16x8 bv3 = *(const bf16x8*)(wk + 1536); \
    acc0 = __builtin_amdgcn_mfma_f32_16x16x32_bf16(a, bv0, acc0, 0, 0, 0); \
    acc1 = __builtin_amdgcn_mfma_f32_16x16x32_bf16(a, bv1, acc1, 0, 0, 0); \
    acc2 = __builtin_amdgcn_mfma_f32_16x16x32_bf16(a, bv2, acc2, 0, 0, 0); \
    acc3 = __builtin_amdgcn_mfma_f32_16x16x32_bf16(a, bv3, acc3, 0, 0, 0); }

#define STORE_H(ACC, NT, DST, STRIDE, BS) if (rb < nv) { \
    int n = (w << 6) + ((NT) << 4) + lane15; \
    float bb = BS[n]; \
    DST[(rb + 0) * STRIDE + n] = __float2bfloat16(ftanh(ACC[0] + bb)); \
    DST[(rb + 1) * STRIDE + n] = __float2bfloat16(ftanh(ACC[1] + bb)); \
    DST[(rb + 2) * STRIDE + n] = __float2bfloat16(ftanh(ACC[2] + bb)); \
    DST[(rb + 3) * STRIDE + n] = __float2bfloat16(ftanh(ACC[3] + bb)); }

    #pragma unroll 2
    for (int ks = 0; ks < 11; ++ks) KSTEP(Dld, 360, ks)
    STORE_H(acc0, 0, Hld, 264, b1s)
    STORE_H(acc1, 1, Hld, 264, b1s)
    STORE_H(acc2, 2, Hld, 264, b1s)
    STORE_H(acc3, 3, Hld, 264, b1s)
    __syncthreads();

    acc0 = (f32x4){0,0,0,0}; acc1 = acc0; acc2 = acc0; acc3 = acc0;
    #pragma unroll 2
    for (int ks = 0; ks < 8; ++ks) KSTEP(Hld, 264, 11 + ks)
    __syncthreads();
    STORE_H(acc0, 0, Dld, 360, b2s)
    STORE_H(acc1, 1, Dld, 360, b2s)
    STORE_H(acc2, 2, Dld, 360, b2s)
    STORE_H(acc3, 3, Dld, 360, b2s)
    __syncthreads();

    acc0 = (f32x4){0,0,0,0}; acc1 = acc0; acc2 = acc0; acc3 = acc0;
    #pragma unroll 2
    for (int ks = 0; ks < 8; ++ks) KSTEP(Dld, 360, 19 + ks)

    float s0 = 0.f, s1 = 0.f, s2 = 0.f, s3 = 0.f;
#define EPART(ACC, NT) if (rb < nv) { \
    int n = (w << 6) + ((NT) << 4) + lane15; \
    float wv = w4s[n]; float bb = b3s[n]; \
    s0 += ftanh(ACC[0] + bb) * wv; s1 += ftanh(ACC[1] + bb) * wv; \
    s2 += ftanh(ACC[2] + bb) * wv; s3 += ftanh(ACC[3] + bb) * wv; }
    EPART(acc0, 0) EPART(acc1, 1) EPART(acc2, 2) EPART(acc3, 3)

    #pragma unroll
    for (int off = 1; off <= 8; off <<= 1) {
        s0 += __shfl_xor(s0, off);
        s1 += __shfl_xor(s1, off);
        s2 += __shfl_xor(s2, off);
        s3 += __shfl_xor(s3, off);
    }
    if (lane15 == 0) {
        red[w][rb + 0] = s0;
        red[w][rb + 1] = s1;
        red[w][rb + 2] = s2;
        red[w][rb + 3] = s3;
    }
    __syncthreads();

    if (tid < 16) {
        float e = red[0][tid] + red[1][tid] + red[2][tid] + red[3][tid];
        e = (tid < nv) ? (e + b4[t]) : 0.0f;
        #pragma unroll
        for (int off = 1; off <= 8; off <<= 1) e += __shfl_xor(e, off);
        if (tid == 0) atomicAdd(out, e);
    }
#undef KSTEP
#undef STORE_H
#undef EPART
}

extern "C" void kernel_launch(void* const* d_in, const int* in_sizes, int n_in,
                              void* d_out, int out_size, void* d_ws, size_t ws_size,
                              hipStream_t stream) {
    const float* xyz   = (const float*)d_in[0];
    const float* box   = (const float*)d_in[1];
    const int*   types = (const int*)  d_in[2];
    const float* w1 = (const float*)d_in[3];
    const float* b1 = (const float*)d_in[4];
    const float* w2 = (const float*)d_in[5];
    const float* b2 = (const float*)d_in[6];
    const float* w3 = (const float*)d_in[7];
    const float* b3 = (const float*)d_in[8];
    const float* w4 = (const float*)d_in[9];
    const float* b4 = (const float*)d_in[10];
    float* out = (float*)d_out;

    // workspace (4B units; 16B alignment preserved at packed/descB)
    float* p = (float*)d_ws;
    int*    cnt      = (int*)p;        p += 16;
    int*    slabOffG = (int*)p;        p += 68;
    int*    posArr   = (int*)p;        p += N_ATOMS;
    int*    lists    = (int*)p;        p += 2 * N_ATOMS;
    p += 12;                                            // pad to 16B
    float4* packed   = (float4*)p;     p += 2 * PSTRIDE * 4;
    float*  lfD      = p;              p += 4 * N_ATOMS;
    int*    lfJ      = (int*)p;        p += 4 * N_ATOMS;
    float*  aX       = p;              p += 96 * N_ATOMS;
    float*  aD       = p;              p += 32 * N_ATOMS;
    __hip_bfloat16* descB = (__hip_bfloat16*)p;         // 2*4096*256 bf16
    p += (size_t)2 * N_ATOMS * 256 / 2;
    __hip_bfloat16* Wp = (__hip_bfloat16*)p;            // 2*27*16*512 bf16
    p += (size_t)2 * KSTEPS_TOTAL * 16 * 512 / 2;

    fill_kernel<<<16 + (2 * 864 * 256) / 256, 256, 0, stream>>>(
        xyz, types, slabOffG, cnt, lists, posArr, packed, out, w1, w2, w3, Wp);
    select_kernel<<<2 * N_ATOMS, 256, 0, stream>>>(
        xyz, box, cnt, packed, slabOffG, types, posArr, descB, aX, aD, lfD, lfJ);
    dim3 g(N_ATOMS / 8, 2);
    mlp_fused_kernel<<<g, 256, 0, stream>>>(cnt, lists, xyz, box, aX, aD, lfD, lfJ,
                                            descB, Wp, b1, b2, b3, w4, b4, out);
}